// Round 15
// baseline (370.880 us; speedup 1.0000x reference)
//
#include <hip/hip_runtime.h>
#include <hip/hip_bf16.h>
#include <math.h>
#include <stdint.h>

#define NNODES 50000
#define SCHUNK 4096
#define AW 1664          // A row width: 3*512 aggx + 128 x
#define XOFF 1536        // x-slice offset within A row

typedef __bf16 bf16x8 __attribute__((ext_vector_type(8)));
typedef float f32x4 __attribute__((ext_vector_type(4)));
typedef float f32x2 __attribute__((ext_vector_type(2)));
typedef unsigned short u16;
typedef unsigned int u32;
typedef u32 u32x4 __attribute__((ext_vector_type(4)));

__device__ __forceinline__ float lrelu(float x){ return x >= 0.f ? x : 0.2f*x; }
__device__ __forceinline__ float lo2f(u32 v){ union{ u32 i; float f; } c; c.i = v<<16; return c.f; }
__device__ __forceinline__ float hi2f(u32 v){ union{ u32 i; float f; } c; c.i = v & 0xffff0000u; return c.f; }
__device__ __forceinline__ f32x2 up2(u32 v){ f32x2 r; r.x = lo2f(v); r.y = hi2f(v); return r; }
__device__ __forceinline__ u16 f2b(float f){ __hip_bfloat16 h = __float2bfloat16(f); return *(u16*)&h; }
__device__ __forceinline__ u32 packbf(float a, float b){ return (u32)f2b(a) | ((u32)f2b(b) << 16); }

// global -> LDS direct DMA, 16B per lane, LDS dest = wave-uniform base + lane*16
#define GLDS16(g, l) __builtin_amdgcn_global_load_lds( \
    (const __attribute__((address_space(1))) void*)(g), \
    (__attribute__((address_space(3))) void*)(l), 16, 0, 0)

// ---- prep (merged): stacked B (row-major [128][AW]) + bias fold + wl + fcW^T + cnt zero ----
__global__ void prep_all(const float* __restrict__ W0, const float* __restrict__ W1,
                         const float* __restrict__ resW0, const float* __restrict__ resW1,
                         const float* __restrict__ b0, const float* __restrict__ b1,
                         const float* __restrict__ al0, const float* __restrict__ ar0,
                         const float* __restrict__ al1, const float* __restrict__ ar1,
                         const float* __restrict__ fcW,
                         u16* __restrict__ Btb, float* __restrict__ biasf,
                         u16* __restrict__ wlb, u16* __restrict__ fcWtb,
                         int* __restrict__ cnt)
{
    int gid = blockIdx.x*blockDim.x + threadIdx.x;
    if (gid < 3*NNODES) cnt[gid] = 0;
    if (gid < 2*128*AW){
        int l = gid / (128*AW);
        int rem = gid - l*(128*AW);
        int c = rem / AW;
        int j = rem - c*AW;
        const float* W  = l ? W1 : W0;
        const float* rw = l ? resW1 : resW0;
        float v;
        if (j < XOFF){
            int r = j >> 9, h = (j >> 7) & 3, k = j & 127;
            v = 0.25f * W[(size_t)r*65536 + (size_t)k*512 + h*128 + c];
        } else {
            int k = j - XOFF;
            float s = 0.f;
            for (int r = 0; r < 3; ++r)
                for (int h = 0; h < 4; ++h)
                    s += rw[(size_t)r*65536 + (size_t)k*512 + h*128 + c];
            v = 0.25f * s;
        }
        Btb[gid] = f2b(v);
    }
    if (gid < 256){
        int l = gid >> 7, c = gid & 127;
        const float* bb = l ? b1 : b0;
        float s = 0.f;
        for (int r = 0; r < 3; ++r)
            for (int h = 0; h < 4; ++h)
                s += bb[r*512 + h*128 + c];
        biasf[gid] = 0.25f*s;
    }
    if (gid < 2*128*128){
        int l = gid >> 14;
        int col = (gid >> 7) & 127;
        int k = gid & 127;
        float v = 0.f;
        if (col < 24){
            int r = col >> 3, lr = (col >> 2) & 1, h = col & 3;
            const float* W = l ? W1 : W0;
            const float* av = l ? (lr ? ar1 : al1) : (lr ? ar0 : al0);
            const float* wrow = W + (size_t)r*65536 + (size_t)k*512 + h*128;
            const float* arow = av + r*512 + h*128;
            for (int cc = 0; cc < 128; ++cc) v += wrow[cc]*arow[cc];
        }
        wlb[gid] = f2b(v);
    }
    if (gid < 128*128){
        int k = gid & 127, n = gid >> 7;
        fcWtb[gid] = f2b(fcW[k*128 + n]);
    }
}

// ---- xprep + hist packed in one launch ----
// Blocks [0, MBX): x fp32 -> bf16 Ax (stride AW) + el0 = x @ wl0 via MFMA.
// Blocks [MBX, ...): dst histogram (atomics on cnt, zeroed by prep_all).
__global__ __launch_bounds__(256) void xprep_hist(const float* __restrict__ x,
    u16* __restrict__ Ax, const u16* __restrict__ wl, float* __restrict__ el, int M, int MBX,
    const int* __restrict__ d0, const int* __restrict__ d1, const int* __restrict__ d2,
    int e0, int e1, int e2, int* __restrict__ cnt)
{
    const int tid = threadIdx.x;
    if (blockIdx.x >= MBX){
        int g = (blockIdx.x - MBX)*256 + tid;
        if (g < e0 + e1 + e2){
            int rel, idx;
            if (g < e0){ rel = 0; idx = g; }
            else if (g < e0 + e1){ rel = 1; idx = g - e0; }
            else { rel = 2; idx = g - e0 - e1; }
            const int* d = rel == 0 ? d0 : (rel == 1 ? d1 : d2);
            atomicAdd(cnt + (size_t)rel*NNODES + d[idx], 1);
        }
        return;
    }
    __shared__ u16 Xs[64*136];
    __shared__ u16 Ws[32*136];
    const int row0 = blockIdx.x*64;
    #pragma unroll
    for (int p = 0; p < 2; ++p){
        int idx = tid + p*256;
        int c = idx >> 4, kc = (idx & 15)*8;
        float4 v = make_float4(0.f,0.f,0.f,0.f);
        if (c < 24) v = *(const float4*)(wl + c*128 + kc);
        *(float4*)&Ws[c*136 + kc] = v;
    }
    int r = tid >> 2, cq = (tid & 3)*32;
    int grow = row0 + r;
    if (grow < M){
        #pragma unroll
        for (int i = 0; i < 8; ++i){
            float4 v = *(const float4*)(x + (size_t)grow*128 + cq + i*4);
            ushort4 o;
            o.x = f2b(v.x); o.y = f2b(v.y); o.z = f2b(v.z); o.w = f2b(v.w);
            *(ushort4*)(Ax + (size_t)grow*AW + cq + i*4) = o;
            *(ushort4*)&Xs[r*136 + cq + i*4] = o;
        }
    } else {
        ushort4 z; z.x=0; z.y=0; z.z=0; z.w=0;
        #pragma unroll
        for (int i = 0; i < 8; ++i) *(ushort4*)&Xs[r*136 + cq + i*4] = z;
    }
    __syncthreads();
    const int lane = tid & 63, wave = tid >> 6;
    const int r16 = lane & 15, quad = lane >> 4;
    f32x4 acc0 = {}, acc1 = {};
    #pragma unroll
    for (int ks = 0; ks < 4; ++ks){
        int ko = ks*32 + quad*8;
        bf16x8 a  = *(const bf16x8*)&Xs[(wave*16 + r16)*136 + ko];
        bf16x8 b0 = *(const bf16x8*)&Ws[r16*136 + ko];
        bf16x8 b1 = *(const bf16x8*)&Ws[(16 + r16)*136 + ko];
        acc0 = __builtin_amdgcn_mfma_f32_16x16x32_bf16(a, b0, acc0, 0,0,0);
        acc1 = __builtin_amdgcn_mfma_f32_16x16x32_bf16(a, b1, acc1, 0,0,0);
    }
    #pragma unroll
    for (int p = 0; p < 4; ++p){
        int row = row0 + wave*16 + quad*4 + p;
        if (row < M){
            el[(size_t)row*32 + r16] = acc0[p];
            if (r16 < 8) el[(size_t)row*32 + 16 + r16] = acc1[p];
        }
    }
}

// ---- single-pass scan (merged scan_part + scan_write) ----
__global__ __launch_bounds__(256) void scan_all(const int* __restrict__ cnt_all,
                                                int* __restrict__ rp_all, int* __restrict__ cur_all,
                                                int Nn, int nblk)
{
    int rel = blockIdx.y, blk = blockIdx.x;
    const int* cnt = cnt_all + (size_t)rel*Nn;
    int* rp  = rp_all  + (size_t)rel*(Nn+1);
    int* cur = cur_all + (size_t)rel*Nn;
    int tid = threadIdx.x;
    __shared__ int wsA[4];
    __shared__ int wsum[4];
    __shared__ int sOffS;
    int pre = blk*SCHUNK;
    int s0 = 0;
    for (int i = tid*4; i < pre; i += 1024){
        int4 v = *(const int4*)(cnt + i);
        s0 += v.x + v.y + v.z + v.w;
    }
    #pragma unroll
    for (int off = 1; off < 64; off <<= 1) s0 += __shfl_xor(s0, off);
    if ((tid & 63) == 0) wsA[tid >> 6] = s0;
    __syncthreads();
    if (tid == 0) sOffS = wsA[0] + wsA[1] + wsA[2] + wsA[3];
    int i0 = blk*SCHUNK + tid*16;
    int v[16];
    int s = 0;
    #pragma unroll
    for (int k = 0; k < 16; ++k){
        int idx = i0 + k;
        v[k] = (idx < Nn) ? cnt[idx] : 0;
        s += v[k];
    }
    int lane = tid & 63;
    int incl = s;
    #pragma unroll
    for (int off = 1; off < 64; off <<= 1){
        int t = __shfl_up(incl, off);
        if (lane >= off) incl += t;
    }
    if (lane == 63) wsum[tid >> 6] = incl;
    __syncthreads();
    int sOff = sOffS;
    int woff = 0;
    for (int w = 0; w < (tid >> 6); ++w) woff += wsum[w];
    int ex = sOff + woff + incl - s;
    #pragma unroll
    for (int k = 0; k < 16; ++k){
        int idx = i0 + k;
        if (idx < Nn){ rp[idx] = ex; cur[idx] = ex; }
        ex += v[k];
    }
    if (blk == nblk - 1 && tid == 0)
        rp[Nn] = sOff + wsum[0] + wsum[1] + wsum[2] + wsum[3];
}

__global__ void scatter_all(const int* __restrict__ s0, const int* __restrict__ s1,
                            const int* __restrict__ s2,
                            const int* __restrict__ d0, const int* __restrict__ d1,
                            const int* __restrict__ d2, int e0, int e1, int e2,
                            int* __restrict__ cur, int* __restrict__ colb)
{
    int g = blockIdx.x*blockDim.x + threadIdx.x;
    if (g >= e0 + e1 + e2) return;
    int rel, idx, coff;
    if (g < e0){ rel = 0; idx = g; coff = 0; }
    else if (g < e0 + e1){ rel = 1; idx = g - e0; coff = e0; }
    else { rel = 2; idx = g - e0 - e1; coff = e0 + e1; }
    const int* sp = rel == 0 ? s0 : (rel == 1 ? s1 : s2);
    const int* dp = rel == 0 ? d0 : (rel == 1 ? d1 : d2);
    int d = dp[idx];
    int pos = atomicAdd(cur + (size_t)rel*NNODES + d, 1);
    colb[coff + pos] = sp[idx];
}

// ---- 16-lanes-per-node aggregation, lane-parallel edge metadata ----
// NONTEMPORAL Abuf stores (via clang ext_vector u32x4): the 150MB write stream
// bypasses cache allocation, keeping the 25.6MB x-region L3-resident so
// gathers hit cache instead of HBM (measured FETCH 76MB vs 25MB compulsory).
__global__ __launch_bounds__(256) void agg3(const int* __restrict__ rowp_all,
    const int* __restrict__ colb_all, int e0, int e01,
    const float* __restrict__ el_all,
    const u16* __restrict__ Ax, u16* __restrict__ Abuf, int Nn)
{
    const int rel = blockIdx.y;
    const int tid = threadIdx.x;
    const int lane = tid & 63;
    const int o = tid & 15;                     // lane within node-group
    const int base = lane & 48;                 // group base within wave
    const int n = (blockIdx.x*256 + tid) >> 4;  // node
    if (n >= Nn) return;
    const int* rowp = rowp_all + (size_t)rel*(Nn+1);
    const int coff = (rel == 0) ? 0 : ((rel == 1) ? e0 : e01);
    const int* colb = colb_all + coff;
    u16* op = Abuf + (size_t)n*AW + rel*512 + o*8;

    int beg = rowp[n], end = rowp[n+1];
    if (beg >= end){
        u32x4 z = {0, 0, 0, 0};
        #pragma unroll
        for (int h = 0; h < 4; ++h)
            __builtin_nontemporal_store(z, (u32x4*)(op + h*128));
        return;
    }
    float4 ed = *(const float4*)(el_all + (size_t)n*32 + rel*8 + 4);
    f32x2 acc2[4][4] = {};     // [head][col-pair]
    float us0 = 0.f, us1 = 0.f, us2 = 0.f, us3 = 0.f;

    for (int eb = beg; eb < end; eb += 16){
        int rem = end - eb;
        int cnt16 = rem < 16 ? rem : 16;
        bool val = (o < cnt16);
        int s_l = 0;
        if (val) s_l = colb[eb + o];
        float wl0 = 0.f, wl1 = 0.f, wl2 = 0.f, wl3 = 0.f;
        if (val){
            float4 e_l = *(const float4*)(el_all + (size_t)s_l*32 + rel*8);
            wl0 = __expf(lrelu(e_l.x + ed.x));
            wl1 = __expf(lrelu(e_l.y + ed.y));
            wl2 = __expf(lrelu(e_l.z + ed.z));
            wl3 = __expf(lrelu(e_l.w + ed.w));
        }
        us0 += wl0; us1 += wl1; us2 += wl2; us3 += wl3;
        // 2-deep gather pipeline, addresses via shfl
        int st0 = __shfl(s_l, base);
        uint4 xa = *(const uint4*)(Ax + (size_t)st0*AW + o*8);
        uint4 xb = xa;
        if (cnt16 > 1){
            int st1 = __shfl(s_l, base + 1);
            xb = *(const uint4*)(Ax + (size_t)st1*AW + o*8);
        }
        for (int t = 0; t < cnt16; ++t){
            uint4 xc = xb;
            if (t + 2 < cnt16){
                int st2 = __shfl(s_l, base + t + 2);
                xc = *(const uint4*)(Ax + (size_t)st2*AW + o*8);
            }
            f32x2 w0p, w1p, w2p, w3p;
            { float w = __shfl(wl0, base + t); w0p.x = w; w0p.y = w; }
            { float w = __shfl(wl1, base + t); w1p.x = w; w1p.y = w; }
            { float w = __shfl(wl2, base + t); w2p.x = w; w2p.y = w; }
            { float w = __shfl(wl3, base + t); w3p.x = w; w3p.y = w; }
            f32x2 xv[4];
            xv[0] = up2(xa.x); xv[1] = up2(xa.y); xv[2] = up2(xa.z); xv[3] = up2(xa.w);
            #pragma unroll
            for (int c = 0; c < 4; ++c){
                acc2[0][c] += w0p * xv[c];
                acc2[1][c] += w1p * xv[c];
                acc2[2][c] += w2p * xv[c];
                acc2[3][c] += w3p * xv[c];
            }
            xa = xb; xb = xc;
        }
    }
    // reduce weight sums across the 16-lane group
    #pragma unroll
    for (int off = 1; off < 16; off <<= 1){
        us0 += __shfl_xor(us0, off); us1 += __shfl_xor(us1, off);
        us2 += __shfl_xor(us2, off); us3 += __shfl_xor(us3, off);
    }
    float inv[4] = {1.f/us0, 1.f/us1, 1.f/us2, 1.f/us3};
    #pragma unroll
    for (int h = 0; h < 4; ++h){
        u32x4 ov;
        ov.x = packbf(acc2[h][0].x*inv[h], acc2[h][0].y*inv[h]);
        ov.y = packbf(acc2[h][1].x*inv[h], acc2[h][1].y*inv[h]);
        ov.z = packbf(acc2[h][2].x*inv[h], acc2[h][2].y*inv[h]);
        ov.w = packbf(acc2[h][3].x*inv[h], acc2[h][3].y*inv[h]);
        __builtin_nontemporal_store(ov, (u32x4*)(op + h*128));
    }
}

// ---- bf16 MFMA GEMM, 128x128 tile, BK=64, DOUBLE-BUFFERED (64KB LDS) ----
// Minimum 2-phase: STAGE(t+1) issued BEFORE compute(t); one barrier per
// K-step (its implicit vmcnt(0) drains after 32 MFMAs, not before them).
// FCF=1 (layer 0): fused fc epilogue (Cs[128][136] + Ws[64][136] = 51KB).
template<int EPI, int FCF>
__global__ __launch_bounds__(256, 2) void gemm_f(
    const u16* __restrict__ A, int Astride, int K,
    const u16* __restrict__ Bt,
    float* __restrict__ Cf, u16* __restrict__ Cb, int Cstride, int M,
    const float* __restrict__ bias, const float* __restrict__ gamma,
    const float* __restrict__ beta, const float* __restrict__ mean,
    const float* __restrict__ var,
    const u16* __restrict__ wl, float* __restrict__ el,
    const u16* __restrict__ fcw, const float* __restrict__ fcb2)
{
    __shared__ u16 smem[32768];      // 2 x (As 16KB + Bs 16KB) = 64KB; epilogue reuses 51KB
    const int tid = threadIdx.x;
    const int row0 = blockIdx.x*128;
    const int lane = tid & 63, wave = tid >> 6;
    const int wm = (wave >> 1)*64, wn = (wave & 1)*64;
    const int r16 = lane & 15, quad = lane >> 4;
    const int swzbase = r16 & 7;
    f32x4 acc[4][4] = {};

    // staging geometry: lane covers row-residue r8, 16B chunk jc (pre-swizzled source)
    const int r8 = lane >> 3, jc = lane & 7;
    const int soff = ((jc ^ r8) << 3);
    const u16* srcA[4];
    const u16* srcB[4];
    #pragma unroll
    for (int g = 0; g < 4; ++g){
        int gr = row0 + wave*32 + g*8 + r8;
        if (gr >= M) gr = M - 1;
        srcA[g] = A + (size_t)gr*Astride + soff;
        srcB[g] = Bt + (size_t)(wave*32 + g*8 + r8)*K + soff;
    }
    const int nk = K >> 6;

    #define STAGE(buf, t) do { \
        u16* As_ = smem + (buf)*16384; \
        u16* Bs_ = As_ + 8192; \
        const int k0_ = (t) << 6; \
        _Pragma("unroll") \
        for (int g_ = 0; g_ < 4; ++g_){ \
            GLDS16(srcA[g_] + k0_, As_ + wave*2048 + g_*512); \
            GLDS16(srcB[g_] + k0_, Bs_ + wave*2048 + g_*512); \
        } \
    } while (0)

    STAGE(0, 0);
    __syncthreads();
    for (int t = 0; t < nk; ++t){
        if (t + 1 < nk) STAGE((t+1)&1, t+1);
        const u16* As = smem + (t&1)*16384;
        const u16* Bs = As + 8192;
        #pragma unroll
        for (int ks = 0; ks < 2; ++ks){
            int swz = ((ks*4 + quad) ^ swzbase) << 3;
            bf16x8 a[4], b[4];
            #pragma unroll
            for (int i = 0; i < 4; ++i) a[i] = *(const bf16x8*)&As[(wm + i*16 + r16)*64 + swz];
            #pragma unroll
            for (int j = 0; j < 4; ++j) b[j] = *(const bf16x8*)&Bs[(wn + j*16 + r16)*64 + swz];
            #pragma unroll
            for (int i = 0; i < 4; ++i)
                #pragma unroll
                for (int j = 0; j < 4; ++j)
                    acc[i][j] = __builtin_amdgcn_mfma_f32_16x16x32_bf16(a[i], b[j], acc[i][j], 0,0,0);
        }
        __syncthreads();
    }
    #undef STAGE

    if (!FCF){
        // plain epilogue (layer 1): bias + write
        #pragma unroll
        for (int i = 0; i < 4; ++i){
            #pragma unroll
            for (int p = 0; p < 4; ++p){
                int row = row0 + wm + i*16 + quad*4 + p;
                #pragma unroll
                for (int j = 0; j < 4; ++j){
                    int col = wn + j*16 + r16;
                    float v = acc[i][j][p] + bias[col];
                    if (row < M){
                        if (EPI == 1) Cf[(size_t)row*Cstride + col] = v;
                        else          Cb[(size_t)row*Cstride + col] = f2b(v);
                    }
                }
            }
        }
    } else {
        u16* Cs = smem;              // [128][136] = 17408 u16
        u16* Ws = smem + 17408;      // [64][136]  =  8704 u16
        // 1) hm (bias added) -> Cs bf16
        #pragma unroll
        for (int i = 0; i < 4; ++i){
            #pragma unroll
            for (int p = 0; p < 4; ++p){
                int rl = wm + i*16 + quad*4 + p;
                #pragma unroll
                for (int j = 0; j < 4; ++j){
                    int col = wn + j*16 + r16;
                    Cs[rl*136 + col] = f2b(acc[i][j][p] + bias[col]);
                }
            }
        }
        __syncthreads();
        // 2) fc in two 64-col halves: wave w -> rows w*32..+31, all cols
        f32x4 fa[2][8] = {};
        #pragma unroll
        for (int hh = 0; hh < 2; ++hh){
            {   // stage fcW rows hh*64..+63 -> Ws (4 thr/row, 32 u16 each)
                int rr = tid >> 2, sg = (tid & 3)*32;
                const u16* src = fcw + (size_t)(hh*64 + rr)*128 + sg;
                #pragma unroll
                for (int q = 0; q < 4; ++q)
                    *(float4*)&Ws[rr*136 + sg + q*8] = *(const float4*)(src + q*8);
            }
            __syncthreads();
            #pragma unroll
            for (int ks = 0; ks < 4; ++ks){
                int ko = ks*32 + quad*8;
                #pragma unroll
                for (int i = 0; i < 2; ++i){
                    bf16x8 a = *(const bf16x8*)&Cs[(wave*32 + i*16 + r16)*136 + ko];
                    #pragma unroll
                    for (int jj = 0; jj < 4; ++jj){
                        bf16x8 b = *(const bf16x8*)&Ws[(jj*16 + r16)*136 + ko];
                        fa[i][hh*4+jj] = __builtin_amdgcn_mfma_f32_16x16x32_bf16(a, b, fa[i][hh*4+jj], 0,0,0);
                    }
                }
            }
            __syncthreads();
        }
        // 3) relu + BN -> global Cb and Cs bf16 (Cs hm reads all done)
        #pragma unroll
        for (int f = 0; f < 8; ++f){
            int col = f*16 + r16;
            float fb = fcb2[col];
            float mn = mean[col];
            float sc = gamma[col]*rsqrtf(var[col] + 1e-5f);
            float bt = beta[col];
            #pragma unroll
            for (int i = 0; i < 2; ++i){
                #pragma unroll
                for (int p = 0; p < 4; ++p){
                    int rl = wave*32 + i*16 + quad*4 + p;
                    int row = row0 + rl;
                    float v = fa[i][f][p] + fb;
                    v = fmaxf(v, 0.f);
                    v = (v - mn)*sc + bt;
                    u16 vb = f2b(v);
                    if (row < M) Cb[(size_t)row*Cstride + col] = vb;
                    Cs[rl*136 + col] = vb;
                }
            }
        }
        // stage wl (cols 0..23, rest zero) into Ws first 32 rows
        #pragma unroll
        for (int p = 0; p < 2; ++p){
            int idx = tid + p*256;
            int c = idx >> 4, kc = (idx & 15)*8;
            float4 v = make_float4(0.f,0.f,0.f,0.f);
            if (c < 24) v = *(const float4*)(wl + c*128 + kc);
            *(float4*)&Ws[c*136 + kc] = v;
        }
        __syncthreads();
        // 4) el = fc_out @ wl via MFMA
        f32x4 e0[2] = {}, e1[2] = {};
        #pragma unroll
        for (int ks = 0; ks < 4; ++ks){
            int ko = ks*32 + quad*8;
            #pragma unroll
            for (int i = 0; i < 2; ++i){
                bf16x8 a  = *(const bf16x8*)&Cs[(wave*32 + i*16 + r16)*136 + ko];
                bf16x8 b0 = *(const bf16x8*)&Ws[r16*136 + ko];
                bf16x8 b1 = *(const bf16x8*)&Ws[(16 + r16)*136 + ko];
                e0[i] = __builtin_amdgcn_mfma_f32_16x16x32_bf16(a, b0, e0[i], 0,0,0);
                e1[i] = __builtin_amdgcn_mfma_f32_16x16x32_bf16(a, b1, e1[i], 0,0,0);
            }
        }
        #pragma unroll
        for (int i = 0; i < 2; ++i){
            #pragma unroll
            for (int p = 0; p < 4; ++p){
                int row = row0 + wave*32 + i*16 + quad*4 + p;
                if (row < M){
                    el[(size_t)row*32 + r16] = e0[i][p];
                    if (r16 < 8) el[(size_t)row*32 + 16 + r16] = e1[i][p];
                }
            }
        }
    }
}

static inline char* align256(char* p){ return (char*)(((uintptr_t)p + 255) & ~(uintptr_t)255); }

extern "C" void kernel_launch(void* const* d_in, const int* in_sizes, int n_in,
                              void* d_out, int out_size, void* d_ws, size_t ws_size,
                              hipStream_t stream)
{
    const float* x      = (const float*)d_in[0];
    const int* srcs[3]  = {(const int*)d_in[1], (const int*)d_in[3], (const int*)d_in[5]};
    const int* dsts[3]  = {(const int*)d_in[2], (const int*)d_in[4], (const int*)d_in[6]};
    const int  E[3]     = {in_sizes[1], in_sizes[3], in_sizes[5]};
    const float* W0     = (const float*)d_in[7];
    const float* al0    = (const float*)d_in[8];
    const float* ar0    = (const float*)d_in[9];
    const float* resW0  = (const float*)d_in[10];
    const float* b0     = (const float*)d_in[11];
    const float* W1     = (const float*)d_in[12];
    const float* al1    = (const float*)d_in[13];
    const float* ar1    = (const float*)d_in[14];
    const float* resW1  = (const float*)d_in[15];
    const float* b1     = (const float*)d_in[16];
    const float* fcW    = (const float*)d_in[17];
    const float* fcb    = (const float*)d_in[18];
    const float* gamma  = (const float*)d_in[19];
    const float* beta   = (const float*)d_in[20];
    const float* bmean  = (const float*)d_in[21];
    const float* bvar   = (const float*)d_in[22];
    float* out = (float*)d_out;

    // workspace carve
    char* p = (char*)d_ws;
    u16*   Abuf  = (u16*)p;   p += (size_t)NNODES*AW*2;    p = align256(p);
    float* el    = (float*)p; p += (size_t)NNODES*32*4;    p = align256(p);
    int*   cnt   = (int*)p;   p += (size_t)3*NNODES*4;     p = align256(p);
    int*   rowp  = (int*)p;   p += (size_t)3*(NNODES+1)*4; p = align256(p);
    int*   cur   = (int*)p;   p += (size_t)3*NNODES*4;     p = align256(p);
    int*   colb  = (int*)p;   p += (size_t)(E[0]+E[1]+E[2])*4; p = align256(p);
    u16*   Btb   = (u16*)p;   p += (size_t)2*128*AW*2;     p = align256(p);
    u16*   wlb   = (u16*)p;   p += (size_t)2*128*128*2;    p = align256(p);
    u16*   fcWtb = (u16*)p;   p += (size_t)128*128*2;      p = align256(p);
    float* biasf = (float*)p; p += (size_t)2*128*4;        p = align256(p);

    const int NBLK = (NNODES + SCHUNK - 1)/SCHUNK;
    const int MB64 = (NNODES + 63)/64;
    const int MBG  = (NNODES + 127)/128;
    const int AGGBLKS = (NNODES*16 + 255)/256;   // 16 lanes per node
    const int ETOT = E[0] + E[1] + E[2];
    const int HISTB = (ETOT + 255)/256;
    dim3 blk(256);
    u16* Ax = Abuf + XOFF;

    prep_all<<<(2*128*AW + 255)/256, blk, 0, stream>>>(W0, W1, resW0, resW1, b0, b1,
                                                       al0, ar0, al1, ar1, fcW,
                                                       Btb, biasf, wlb, fcWtb, cnt);
    xprep_hist<<<MB64 + HISTB, blk, 0, stream>>>(x, Ax, wlb, el, NNODES, MB64,
                                                 dsts[0], dsts[1], dsts[2],
                                                 E[0], E[1], E[2], cnt);
    scan_all<<<dim3(NBLK,3), blk, 0, stream>>>(cnt, rowp, cur, NNODES, NBLK);
    scatter_all<<<(ETOT + 255)/256, blk, 0, stream>>>(srcs[0], srcs[1], srcs[2],
                                                      dsts[0], dsts[1], dsts[2],
                                                      E[0], E[1], E[2], cur, colb);

    // ---- layer 0 (agg with inline weights -> big GEMM with fused fc+BN+el) ----
    agg3<<<dim3(AGGBLKS,3), blk, 0, stream>>>(rowp, colb, E[0], E[0]+E[1], el, Ax, Abuf, NNODES);
    gemm_f<0,1><<<MBG, blk, 0, stream>>>(Abuf, AW, AW, Btb, nullptr, Ax, AW, NNODES,
                                         biasf, gamma, beta, bmean, bvar,
                                         wlb + 16384, el, fcWtb, fcb);

    // ---- layer 1 ----
    agg3<<<dim3(AGGBLKS,3), blk, 0, stream>>>(rowp, colb, E[0], E[0]+E[1], el, Ax, Abuf, NNODES);
    gemm_f<1,0><<<MBG, blk, 0, stream>>>(Abuf, AW, AW, Btb + (size_t)128*AW, out, nullptr, 128, NNODES,
                                         biasf + 128, nullptr, nullptr, nullptr, nullptr,
                                         nullptr, nullptr, nullptr, nullptr);
}

// Round 17
// 349.742 us; speedup vs baseline: 1.0604x; 1.0604x over previous
//
#include <hip/hip_runtime.h>
#include <hip/hip_bf16.h>
#include <math.h>
#include <stdint.h>

#define NNODES 50000
#define SCHUNK 4096
#define AW 1664          // A row width: 3*512 aggx + 128 x
#define XOFF 1536        // x-slice offset within A row

typedef __bf16 bf16x8 __attribute__((ext_vector_type(8)));
typedef float f32x4 __attribute__((ext_vector_type(4)));
typedef float f32x2 __attribute__((ext_vector_type(2)));
typedef unsigned short u16;
typedef unsigned int u32;

__device__ __forceinline__ float lrelu(float x){ return x >= 0.f ? x : 0.2f*x; }
__device__ __forceinline__ float lo2f(u32 v){ union{ u32 i; float f; } c; c.i = v<<16; return c.f; }
__device__ __forceinline__ float hi2f(u32 v){ union{ u32 i; float f; } c; c.i = v & 0xffff0000u; return c.f; }
__device__ __forceinline__ f32x2 up2(u32 v){ f32x2 r; r.x = lo2f(v); r.y = hi2f(v); return r; }
__device__ __forceinline__ u16 f2b(float f){ __hip_bfloat16 h = __float2bfloat16(f); return *(u16*)&h; }
__device__ __forceinline__ u32 packbf(float a, float b){ return (u32)f2b(a) | ((u32)f2b(b) << 16); }

// global -> LDS direct DMA, 16B per lane, LDS dest = wave-uniform base + lane*16
#define GLDS16(g, l) __builtin_amdgcn_global_load_lds( \
    (const __attribute__((address_space(1))) void*)(g), \
    (__attribute__((address_space(3))) void*)(l), 16, 0, 0)

// ---- prep (merged): stacked B (row-major [128][AW]) + bias fold + wl + fcW^T + cnt zero ----
__global__ void prep_all(const float* __restrict__ W0, const float* __restrict__ W1,
                         const float* __restrict__ resW0, const float* __restrict__ resW1,
                         const float* __restrict__ b0, const float* __restrict__ b1,
                         const float* __restrict__ al0, const float* __restrict__ ar0,
                         const float* __restrict__ al1, const float* __restrict__ ar1,
                         const float* __restrict__ fcW,
                         u16* __restrict__ Btb, float* __restrict__ biasf,
                         u16* __restrict__ wlb, u16* __restrict__ fcWtb,
                         int* __restrict__ cnt)
{
    int gid = blockIdx.x*blockDim.x + threadIdx.x;
    if (gid < 3*NNODES) cnt[gid] = 0;
    if (gid < 2*128*AW){
        int l = gid / (128*AW);
        int rem = gid - l*(128*AW);
        int c = rem / AW;
        int j = rem - c*AW;
        const float* W  = l ? W1 : W0;
        const float* rw = l ? resW1 : resW0;
        float v;
        if (j < XOFF){
            int r = j >> 9, h = (j >> 7) & 3, k = j & 127;
            v = 0.25f * W[(size_t)r*65536 + (size_t)k*512 + h*128 + c];
        } else {
            int k = j - XOFF;
            float s = 0.f;
            for (int r = 0; r < 3; ++r)
                for (int h = 0; h < 4; ++h)
                    s += rw[(size_t)r*65536 + (size_t)k*512 + h*128 + c];
            v = 0.25f * s;
        }
        Btb[gid] = f2b(v);
    }
    if (gid < 256){
        int l = gid >> 7, c = gid & 127;
        const float* bb = l ? b1 : b0;
        float s = 0.f;
        for (int r = 0; r < 3; ++r)
            for (int h = 0; h < 4; ++h)
                s += bb[r*512 + h*128 + c];
        biasf[gid] = 0.25f*s;
    }
    if (gid < 2*128*128){
        int l = gid >> 14;
        int col = (gid >> 7) & 127;
        int k = gid & 127;
        float v = 0.f;
        if (col < 24){
            int r = col >> 3, lr = (col >> 2) & 1, h = col & 3;
            const float* W = l ? W1 : W0;
            const float* av = l ? (lr ? ar1 : al1) : (lr ? ar0 : al0);
            const float* wrow = W + (size_t)r*65536 + (size_t)k*512 + h*128;
            const float* arow = av + r*512 + h*128;
            for (int cc = 0; cc < 128; ++cc) v += wrow[cc]*arow[cc];
        }
        wlb[gid] = f2b(v);
    }
    if (gid < 128*128){
        int k = gid & 127, n = gid >> 7;
        fcWtb[gid] = f2b(fcW[k*128 + n]);
    }
}

// ---- xprep: x fp32 -> bf16 Ax (stride AW) + el0 = x @ wl0 via MFMA ----
__global__ __launch_bounds__(256) void xprep_kernel(const float* __restrict__ x,
    u16* __restrict__ Ax, const u16* __restrict__ wl, float* __restrict__ el, int M)
{
    __shared__ u16 Xs[64*136];
    __shared__ u16 Ws[32*136];
    const int tid = threadIdx.x;
    const int row0 = blockIdx.x*64;
    #pragma unroll
    for (int p = 0; p < 2; ++p){
        int idx = tid + p*256;
        int c = idx >> 4, kc = (idx & 15)*8;
        float4 v = make_float4(0.f,0.f,0.f,0.f);
        if (c < 24) v = *(const float4*)(wl + c*128 + kc);
        *(float4*)&Ws[c*136 + kc] = v;
    }
    int r = tid >> 2, cq = (tid & 3)*32;
    int grow = row0 + r;
    if (grow < M){
        #pragma unroll
        for (int i = 0; i < 8; ++i){
            float4 v = *(const float4*)(x + (size_t)grow*128 + cq + i*4);
            ushort4 o;
            o.x = f2b(v.x); o.y = f2b(v.y); o.z = f2b(v.z); o.w = f2b(v.w);
            *(ushort4*)(Ax + (size_t)grow*AW + cq + i*4) = o;
            *(ushort4*)&Xs[r*136 + cq + i*4] = o;
        }
    } else {
        ushort4 z; z.x=0; z.y=0; z.z=0; z.w=0;
        #pragma unroll
        for (int i = 0; i < 8; ++i) *(ushort4*)&Xs[r*136 + cq + i*4] = z;
    }
    __syncthreads();
    const int lane = tid & 63, wave = tid >> 6;
    const int r16 = lane & 15, quad = lane >> 4;
    f32x4 acc0 = {}, acc1 = {};
    #pragma unroll
    for (int ks = 0; ks < 4; ++ks){
        int ko = ks*32 + quad*8;
        bf16x8 a  = *(const bf16x8*)&Xs[(wave*16 + r16)*136 + ko];
        bf16x8 b0 = *(const bf16x8*)&Ws[r16*136 + ko];
        bf16x8 b1 = *(const bf16x8*)&Ws[(16 + r16)*136 + ko];
        acc0 = __builtin_amdgcn_mfma_f32_16x16x32_bf16(a, b0, acc0, 0,0,0);
        acc1 = __builtin_amdgcn_mfma_f32_16x16x32_bf16(a, b1, acc1, 0,0,0);
    }
    #pragma unroll
    for (int p = 0; p < 4; ++p){
        int row = row0 + wave*16 + quad*4 + p;
        if (row < M){
            el[(size_t)row*32 + r16] = acc0[p];
            if (r16 < 8) el[(size_t)row*32 + 16 + r16] = acc1[p];
        }
    }
}

// ---- CSR build (fused over relations) ----
__global__ void hist_all(const int* __restrict__ d0, const int* __restrict__ d1,
                         const int* __restrict__ d2, int e0, int e1, int e2,
                         int* __restrict__ cnt)
{
    int g = blockIdx.x*blockDim.x + threadIdx.x;
    if (g >= e0 + e1 + e2) return;
    int rel, idx;
    if (g < e0){ rel = 0; idx = g; }
    else if (g < e0 + e1){ rel = 1; idx = g - e0; }
    else { rel = 2; idx = g - e0 - e1; }
    const int* d = rel == 0 ? d0 : (rel == 1 ? d1 : d2);
    atomicAdd(cnt + (size_t)rel*NNODES + d[idx], 1);
}

// ---- single-pass scan (merged scan_part + scan_write) ----
__global__ __launch_bounds__(256) void scan_all(const int* __restrict__ cnt_all,
                                                int* __restrict__ rp_all, int* __restrict__ cur_all,
                                                int Nn, int nblk)
{
    int rel = blockIdx.y, blk = blockIdx.x;
    const int* cnt = cnt_all + (size_t)rel*Nn;
    int* rp  = rp_all  + (size_t)rel*(Nn+1);
    int* cur = cur_all + (size_t)rel*Nn;
    int tid = threadIdx.x;
    __shared__ int wsA[4];
    __shared__ int wsum[4];
    __shared__ int sOffS;
    int pre = blk*SCHUNK;
    int s0 = 0;
    for (int i = tid*4; i < pre; i += 1024){
        int4 v = *(const int4*)(cnt + i);
        s0 += v.x + v.y + v.z + v.w;
    }
    #pragma unroll
    for (int off = 1; off < 64; off <<= 1) s0 += __shfl_xor(s0, off);
    if ((tid & 63) == 0) wsA[tid >> 6] = s0;
    __syncthreads();
    if (tid == 0) sOffS = wsA[0] + wsA[1] + wsA[2] + wsA[3];
    int i0 = blk*SCHUNK + tid*16;
    int v[16];
    int s = 0;
    #pragma unroll
    for (int k = 0; k < 16; ++k){
        int idx = i0 + k;
        v[k] = (idx < Nn) ? cnt[idx] : 0;
        s += v[k];
    }
    int lane = tid & 63;
    int incl = s;
    #pragma unroll
    for (int off = 1; off < 64; off <<= 1){
        int t = __shfl_up(incl, off);
        if (lane >= off) incl += t;
    }
    if (lane == 63) wsum[tid >> 6] = incl;
    __syncthreads();
    int sOff = sOffS;
    int woff = 0;
    for (int w = 0; w < (tid >> 6); ++w) woff += wsum[w];
    int ex = sOff + woff + incl - s;
    #pragma unroll
    for (int k = 0; k < 16; ++k){
        int idx = i0 + k;
        if (idx < Nn){ rp[idx] = ex; cur[idx] = ex; }
        ex += v[k];
    }
    if (blk == nblk - 1 && tid == 0)
        rp[Nn] = sOff + wsum[0] + wsum[1] + wsum[2] + wsum[3];
}

__global__ void scatter_all(const int* __restrict__ s0, const int* __restrict__ s1,
                            const int* __restrict__ s2,
                            const int* __restrict__ d0, const int* __restrict__ d1,
                            const int* __restrict__ d2, int e0, int e1, int e2,
                            int* __restrict__ cur, int* __restrict__ colb)
{
    int g = blockIdx.x*blockDim.x + threadIdx.x;
    if (g >= e0 + e1 + e2) return;
    int rel, idx, coff;
    if (g < e0){ rel = 0; idx = g; coff = 0; }
    else if (g < e0 + e1){ rel = 1; idx = g - e0; coff = e0; }
    else { rel = 2; idx = g - e0 - e1; coff = e0 + e1; }
    const int* sp = rel == 0 ? s0 : (rel == 1 ? s1 : s2);
    const int* dp = rel == 0 ? d0 : (rel == 1 ? d1 : d2);
    int d = dp[idx];
    int pos = atomicAdd(cur + (size_t)rel*NNODES + d, 1);
    colb[coff + pos] = sp[idx];
}

// ---- 16-lanes-per-node aggregation, lane-parallel edge metadata, f32x2 packed FMA ----
__global__ __launch_bounds__(256) void agg3(const int* __restrict__ rowp_all,
    const int* __restrict__ colb_all, int e0, int e01,
    const float* __restrict__ el_all,
    const u16* __restrict__ Ax, u16* __restrict__ Abuf, int Nn)
{
    const int rel = blockIdx.y;
    const int tid = threadIdx.x;
    const int lane = tid & 63;
    const int o = tid & 15;                     // lane within node-group
    const int base = lane & 48;                 // group base within wave
    const int n = (blockIdx.x*256 + tid) >> 4;  // node
    if (n >= Nn) return;
    const int* rowp = rowp_all + (size_t)rel*(Nn+1);
    const int coff = (rel == 0) ? 0 : ((rel == 1) ? e0 : e01);
    const int* colb = colb_all + coff;
    u16* op = Abuf + (size_t)n*AW + rel*512 + o*8;

    int beg = rowp[n], end = rowp[n+1];
    if (beg >= end){
        uint4 z; z.x = 0; z.y = 0; z.z = 0; z.w = 0;
        #pragma unroll
        for (int h = 0; h < 4; ++h) *(uint4*)(op + h*128) = z;
        return;
    }
    float4 ed = *(const float4*)(el_all + (size_t)n*32 + rel*8 + 4);
    f32x2 acc2[4][4] = {};     // [head][col-pair]
    float us0 = 0.f, us1 = 0.f, us2 = 0.f, us3 = 0.f;

    for (int eb = beg; eb < end; eb += 16){
        int rem = end - eb;
        int cnt16 = rem < 16 ? rem : 16;
        bool val = (o < cnt16);
        int s_l = 0;
        if (val) s_l = colb[eb + o];
        float wl0 = 0.f, wl1 = 0.f, wl2 = 0.f, wl3 = 0.f;
        if (val){
            float4 e_l = *(const float4*)(el_all + (size_t)s_l*32 + rel*8);
            wl0 = __expf(lrelu(e_l.x + ed.x));
            wl1 = __expf(lrelu(e_l.y + ed.y));
            wl2 = __expf(lrelu(e_l.z + ed.z));
            wl3 = __expf(lrelu(e_l.w + ed.w));
        }
        us0 += wl0; us1 += wl1; us2 += wl2; us3 += wl3;
        // 2-deep gather pipeline, addresses via shfl (no load-to-address chain)
        int st0 = __shfl(s_l, base);
        uint4 xa = *(const uint4*)(Ax + (size_t)st0*AW + o*8);
        uint4 xb = xa;
        if (cnt16 > 1){
            int st1 = __shfl(s_l, base + 1);
            xb = *(const uint4*)(Ax + (size_t)st1*AW + o*8);
        }
        for (int t = 0; t < cnt16; ++t){
            uint4 xc = xb;
            if (t + 2 < cnt16){
                int st2 = __shfl(s_l, base + t + 2);
                xc = *(const uint4*)(Ax + (size_t)st2*AW + o*8);
            }
            f32x2 w0p, w1p, w2p, w3p;
            { float w = __shfl(wl0, base + t); w0p.x = w; w0p.y = w; }
            { float w = __shfl(wl1, base + t); w1p.x = w; w1p.y = w; }
            { float w = __shfl(wl2, base + t); w2p.x = w; w2p.y = w; }
            { float w = __shfl(wl3, base + t); w3p.x = w; w3p.y = w; }
            f32x2 xv[4];
            xv[0] = up2(xa.x); xv[1] = up2(xa.y); xv[2] = up2(xa.z); xv[3] = up2(xa.w);
            #pragma unroll
            for (int c = 0; c < 4; ++c){
                acc2[0][c] += w0p * xv[c];
                acc2[1][c] += w1p * xv[c];
                acc2[2][c] += w2p * xv[c];
                acc2[3][c] += w3p * xv[c];
            }
            xa = xb; xb = xc;
        }
    }
    // reduce weight sums across the 16-lane group
    #pragma unroll
    for (int off = 1; off < 16; off <<= 1){
        us0 += __shfl_xor(us0, off); us1 += __shfl_xor(us1, off);
        us2 += __shfl_xor(us2, off); us3 += __shfl_xor(us3, off);
    }
    float inv[4] = {1.f/us0, 1.f/us1, 1.f/us2, 1.f/us3};
    #pragma unroll
    for (int h = 0; h < 4; ++h){
        uint4 ov;
        ov.x = packbf(acc2[h][0].x*inv[h], acc2[h][0].y*inv[h]);
        ov.y = packbf(acc2[h][1].x*inv[h], acc2[h][1].y*inv[h]);
        ov.z = packbf(acc2[h][2].x*inv[h], acc2[h][2].y*inv[h]);
        ov.w = packbf(acc2[h][3].x*inv[h], acc2[h][3].y*inv[h]);
        *(uint4*)(op + h*128) = ov;
    }
}

// ---- bf16 MFMA GEMM, 128x128 tile, BK=64, DOUBLE-BUFFERED (64KB LDS) ----
// Minimum 2-phase: STAGE(t+1) issued BEFORE compute(t); one barrier per
// K-step (its implicit vmcnt(0) drains after 32 MFMAs, not before them).
// FCF=1 (layer 0): fused fc epilogue (Cs[128][136] + Ws[64][136] = 51KB).
template<int EPI, int FCF>
__global__ __launch_bounds__(256, 2) void gemm_f(
    const u16* __restrict__ A, int Astride, int K,
    const u16* __restrict__ Bt,
    float* __restrict__ Cf, u16* __restrict__ Cb, int Cstride, int M,
    const float* __restrict__ bias, const float* __restrict__ gamma,
    const float* __restrict__ beta, const float* __restrict__ mean,
    const float* __restrict__ var,
    const u16* __restrict__ wl, float* __restrict__ el,
    const u16* __restrict__ fcw, const float* __restrict__ fcb2)
{
    __shared__ u16 smem[32768];      // 2 x (As 16KB + Bs 16KB) = 64KB; epilogue reuses 51KB
    const int tid = threadIdx.x;
    const int row0 = blockIdx.x*128;
    const int lane = tid & 63, wave = tid >> 6;
    const int wm = (wave >> 1)*64, wn = (wave & 1)*64;
    const int r16 = lane & 15, quad = lane >> 4;
    const int swzbase = r16 & 7;
    f32x4 acc[4][4] = {};

    // staging geometry: lane covers row-residue r8, 16B chunk jc (pre-swizzled source)
    const int r8 = lane >> 3, jc = lane & 7;
    const int soff = ((jc ^ r8) << 3);
    const u16* srcA[4];
    const u16* srcB[4];
    #pragma unroll
    for (int g = 0; g < 4; ++g){
        int gr = row0 + wave*32 + g*8 + r8;
        if (gr >= M) gr = M - 1;
        srcA[g] = A + (size_t)gr*Astride + soff;
        srcB[g] = Bt + (size_t)(wave*32 + g*8 + r8)*K + soff;
    }
    const int nk = K >> 6;

    #define STAGE(buf, t) do { \
        u16* As_ = smem + (buf)*16384; \
        u16* Bs_ = As_ + 8192; \
        const int k0_ = (t) << 6; \
        _Pragma("unroll") \
        for (int g_ = 0; g_ < 4; ++g_){ \
            GLDS16(srcA[g_] + k0_, As_ + wave*2048 + g_*512); \
            GLDS16(srcB[g_] + k0_, Bs_ + wave*2048 + g_*512); \
        } \
    } while (0)

    STAGE(0, 0);
    __syncthreads();
    for (int t = 0; t < nk; ++t){
        if (t + 1 < nk) STAGE((t+1)&1, t+1);
        const u16* As = smem + (t&1)*16384;
        const u16* Bs = As + 8192;
        #pragma unroll
        for (int ks = 0; ks < 2; ++ks){
            int swz = ((ks*4 + quad) ^ swzbase) << 3;
            bf16x8 a[4], b[4];
            #pragma unroll
            for (int i = 0; i < 4; ++i) a[i] = *(const bf16x8*)&As[(wm + i*16 + r16)*64 + swz];
            #pragma unroll
            for (int j = 0; j < 4; ++j) b[j] = *(const bf16x8*)&Bs[(wn + j*16 + r16)*64 + swz];
            #pragma unroll
            for (int i = 0; i < 4; ++i)
                #pragma unroll
                for (int j = 0; j < 4; ++j)
                    acc[i][j] = __builtin_amdgcn_mfma_f32_16x16x32_bf16(a[i], b[j], acc[i][j], 0,0,0);
        }
        __syncthreads();
    }
    #undef STAGE

    if (!FCF){
        // plain epilogue (layer 1): bias + write
        #pragma unroll
        for (int i = 0; i < 4; ++i){
            #pragma unroll
            for (int p = 0; p < 4; ++p){
                int row = row0 + wm + i*16 + quad*4 + p;
                #pragma unroll
                for (int j = 0; j < 4; ++j){
                    int col = wn + j*16 + r16;
                    float v = acc[i][j][p] + bias[col];
                    if (row < M){
                        if (EPI == 1) Cf[(size_t)row*Cstride + col] = v;
                        else          Cb[(size_t)row*Cstride + col] = f2b(v);
                    }
                }
            }
        }
    } else {
        u16* Cs = smem;              // [128][136] = 17408 u16
        u16* Ws = smem + 17408;      // [64][136]  =  8704 u16
        // 1) hm (bias added) -> Cs bf16
        #pragma unroll
        for (int i = 0; i < 4; ++i){
            #pragma unroll
            for (int p = 0; p < 4; ++p){
                int rl = wm + i*16 + quad*4 + p;
                #pragma unroll
                for (int j = 0; j < 4; ++j){
                    int col = wn + j*16 + r16;
                    Cs[rl*136 + col] = f2b(acc[i][j][p] + bias[col]);
                }
            }
        }
        __syncthreads();
        // 2) fc in two 64-col halves: wave w -> rows w*32..+31, all cols
        f32x4 fa[2][8] = {};
        #pragma unroll
        for (int hh = 0; hh < 2; ++hh){
            {   // stage fcW rows hh*64..+63 -> Ws (4 thr/row, 32 u16 each)
                int rr = tid >> 2, sg = (tid & 3)*32;
                const u16* src = fcw + (size_t)(hh*64 + rr)*128 + sg;
                #pragma unroll
                for (int q = 0; q < 4; ++q)
                    *(float4*)&Ws[rr*136 + sg + q*8] = *(const float4*)(src + q*8);
            }
            __syncthreads();
            #pragma unroll
            for (int ks = 0; ks < 4; ++ks){
                int ko = ks*32 + quad*8;
                #pragma unroll
                for (int i = 0; i < 2; ++i){
                    bf16x8 a = *(const bf16x8*)&Cs[(wave*32 + i*16 + r16)*136 + ko];
                    #pragma unroll
                    for (int jj = 0; jj < 4; ++jj){
                        bf16x8 b = *(const bf16x8*)&Ws[(jj*16 + r16)*136 + ko];
                        fa[i][hh*4+jj] = __builtin_amdgcn_mfma_f32_16x16x32_bf16(a, b, fa[i][hh*4+jj], 0,0,0);
                    }
                }
            }
            __syncthreads();
        }
        // 3) relu + BN -> global Cb and Cs bf16 (Cs hm reads all done)
        #pragma unroll
        for (int f = 0; f < 8; ++f){
            int col = f*16 + r16;
            float fb = fcb2[col];
            float mn = mean[col];
            float sc = gamma[col]*rsqrtf(var[col] + 1e-5f);
            float bt = beta[col];
            #pragma unroll
            for (int i = 0; i < 2; ++i){
                #pragma unroll
                for (int p = 0; p < 4; ++p){
                    int rl = wave*32 + i*16 + quad*4 + p;
                    int row = row0 + rl;
                    float v = fa[i][f][p] + fb;
                    v = fmaxf(v, 0.f);
                    v = (v - mn)*sc + bt;
                    u16 vb = f2b(v);
                    if (row < M) Cb[(size_t)row*Cstride + col] = vb;
                    Cs[rl*136 + col] = vb;
                }
            }
        }
        // stage wl (cols 0..23, rest zero) into Ws first 32 rows
        #pragma unroll
        for (int p = 0; p < 2; ++p){
            int idx = tid + p*256;
            int c = idx >> 4, kc = (idx & 15)*8;
            float4 v = make_float4(0.f,0.f,0.f,0.f);
            if (c < 24) v = *(const float4*)(wl + c*128 + kc);
            *(float4*)&Ws[c*136 + kc] = v;
        }
        __syncthreads();
        // 4) el = fc_out @ wl via MFMA
        f32x4 e0[2] = {}, e1[2] = {};
        #pragma unroll
        for (int ks = 0; ks < 4; ++ks){
            int ko = ks*32 + quad*8;
            #pragma unroll
            for (int i = 0; i < 2; ++i){
                bf16x8 a  = *(const bf16x8*)&Cs[(wave*32 + i*16 + r16)*136 + ko];
                bf16x8 b0 = *(const bf16x8*)&Ws[r16*136 + ko];
                bf16x8 b1 = *(const bf16x8*)&Ws[(16 + r16)*136 + ko];
                e0[i] = __builtin_amdgcn_mfma_f32_16x16x32_bf16(a, b0, e0[i], 0,0,0);
                e1[i] = __builtin_amdgcn_mfma_f32_16x16x32_bf16(a, b1, e1[i], 0,0,0);
            }
        }
        #pragma unroll
        for (int i = 0; i < 2; ++i){
            #pragma unroll
            for (int p = 0; p < 4; ++p){
                int row = row0 + wave*32 + i*16 + quad*4 + p;
                if (row < M){
                    el[(size_t)row*32 + r16] = e0[i][p];
                    if (r16 < 8) el[(size_t)row*32 + 16 + r16] = e1[i][p];
                }
            }
        }
    }
}

static inline char* align256(char* p){ return (char*)(((uintptr_t)p + 255) & ~(uintptr_t)255); }

extern "C" void kernel_launch(void* const* d_in, const int* in_sizes, int n_in,
                              void* d_out, int out_size, void* d_ws, size_t ws_size,
                              hipStream_t stream)
{
    const float* x      = (const float*)d_in[0];
    const int* srcs[3]  = {(const int*)d_in[1], (const int*)d_in[3], (const int*)d_in[5]};
    const int* dsts[3]  = {(const int*)d_in[2], (const int*)d_in[4], (const int*)d_in[6]};
    const int  E[3]     = {in_sizes[1], in_sizes[3], in_sizes[5]};
    const float* W0     = (const float*)d_in[7];
    const float* al0    = (const float*)d_in[8];
    const float* ar0    = (const float*)d_in[9];
    const float* resW0  = (const float*)d_in[10];
    const float* b0     = (const float*)d_in[11];
    const float* W1     = (const float*)d_in[12];
    const float* al1    = (const float*)d_in[13];
    const float* ar1    = (const float*)d_in[14];
    const float* resW1  = (const float*)d_in[15];
    const float* b1     = (const float*)d_in[16];
    const float* fcW    = (const float*)d_in[17];
    const float* fcb    = (const float*)d_in[18];
    const float* gamma  = (const float*)d_in[19];
    const float* beta   = (const float*)d_in[20];
    const float* bmean  = (const float*)d_in[21];
    const float* bvar   = (const float*)d_in[22];
    float* out = (float*)d_out;

    // workspace carve
    char* p = (char*)d_ws;
    u16*   Abuf  = (u16*)p;   p += (size_t)NNODES*AW*2;    p = align256(p);
    float* el    = (float*)p; p += (size_t)NNODES*32*4;    p = align256(p);
    int*   cnt   = (int*)p;   p += (size_t)3*NNODES*4;     p = align256(p);
    int*   rowp  = (int*)p;   p += (size_t)3*(NNODES+1)*4; p = align256(p);
    int*   cur   = (int*)p;   p += (size_t)3*NNODES*4;     p = align256(p);
    int*   colb  = (int*)p;   p += (size_t)(E[0]+E[1]+E[2])*4; p = align256(p);
    u16*   Btb   = (u16*)p;   p += (size_t)2*128*AW*2;     p = align256(p);
    u16*   wlb   = (u16*)p;   p += (size_t)2*128*128*2;    p = align256(p);
    u16*   fcWtb = (u16*)p;   p += (size_t)128*128*2;      p = align256(p);
    float* biasf = (float*)p; p += (size_t)2*128*4;        p = align256(p);

    const int NBLK = (NNODES + SCHUNK - 1)/SCHUNK;
    const int MB64 = (NNODES + 63)/64;
    const int MBG  = (NNODES + 127)/128;
    const int AGGBLKS = (NNODES*16 + 255)/256;   // 16 lanes per node
    const int ETOT = E[0] + E[1] + E[2];
    dim3 blk(256);
    u16* Ax = Abuf + XOFF;

    prep_all<<<(2*128*AW + 255)/256, blk, 0, stream>>>(W0, W1, resW0, resW1, b0, b1,
                                                       al0, ar0, al1, ar1, fcW,
                                                       Btb, biasf, wlb, fcWtb, cnt);
    xprep_kernel<<<MB64, blk, 0, stream>>>(x, Ax, wlb, el, NNODES);
    hist_all<<<(ETOT + 255)/256, blk, 0, stream>>>(dsts[0], dsts[1], dsts[2], E[0], E[1], E[2], cnt);
    scan_all<<<dim3(NBLK,3), blk, 0, stream>>>(cnt, rowp, cur, NNODES, NBLK);
    scatter_all<<<(ETOT + 255)/256, blk, 0, stream>>>(srcs[0], srcs[1], srcs[2],
                                                      dsts[0], dsts[1], dsts[2],
                                                      E[0], E[1], E[2], cur, colb);

    // ---- layer 0 (agg with inline weights -> big GEMM with fused fc+BN+el) ----
    agg3<<<dim3(AGGBLKS,3), blk, 0, stream>>>(rowp, colb, E[0], E[0]+E[1], el, Ax, Abuf, NNODES);
    gemm_f<0,1><<<MBG, blk, 0, stream>>>(Abuf, AW, AW, Btb, nullptr, Ax, AW, NNODES,
                                         biasf, gamma, beta, bmean, bvar,
                                         wlb + 16384, el, fcWtb, fcb);

    // ---- layer 1 ----
    agg3<<<dim3(AGGBLKS,3), blk, 0, stream>>>(rowp, colb, E[0], E[0]+E[1], el, Ax, Abuf, NNODES);
    gemm_f<1,0><<<MBG, blk, 0, stream>>>(Abuf, AW, AW, Btb + (size_t)128*AW, out, nullptr, 128, NNODES,
                                         biasf + 128, nullptr, nullptr, nullptr, nullptr,
                                         nullptr, nullptr, nullptr, nullptr);
}